// Round 6
// baseline (62.898 us; speedup 1.0000x reference)
//
#include <hip/hip_runtime.h>
#include <hip/hip_bf16.h>

// RoIAlign3D: features (B=4,C=128,T=16,H=56,W=56) f32, rois (R=128,7) f32
// out (R,C,4,8,8) f32. S=2 sub-samples per axis, mean-pooled.
//
// Pass 1: transpose features -> channel-last bf16 G[b][t][h][w][c] in d_ws.
// Pass 2: gather with per-axis corner dedup on ALL axes (weight folding into
//         4 static slots) + predicated x-loads; 8 blocks/CU for latency hiding.

constexpr int B_ = 4, C_ = 128, T_ = 16, H_ = 56, W_ = 56, R_ = 128;
constexpr int OT = 4, OH = 8, OW = 8;
constexpr int HW = H_ * W_;       // 3136
constexpr int THW = T_ * HW;      // 50176
constexpr size_t G_BYTES = (size_t)B_ * THW * C_ * 2;   // 51,380,224

__device__ __forceinline__ float bf16lo(unsigned u) { return __uint_as_float(u << 16); }
__device__ __forceinline__ float bf16hi(unsigned u) { return __uint_as_float(u & 0xffff0000u); }

__device__ __forceinline__ unsigned pk2(float lo, float hi) {
    unsigned a = (unsigned)__bfloat16_as_ushort(__float2bfloat16(lo));
    unsigned b = (unsigned)__bfloat16_as_ushort(__float2bfloat16(hi));
    return a | (b << 16);
}

__device__ __forceinline__ void axis_interp(float coord, int size,
                                            int& lo, int& hi,
                                            float& wl, float& wh, bool& valid) {
    valid = (coord >= -1.0f) && (coord <= (float)size);
    float c = fminf(fmaxf(coord, 0.0f), (float)(size - 1));
    lo = (int)floorf(c);
    if (lo > size - 1) lo = size - 1;
    hi = min(lo + 1, size - 1);
    float fr = c - (float)lo;
    wl = 1.0f - fr;
    wh = fr;
}

// fold 4 (index,weight) slots: merge duplicate indices into first occurrence
__device__ __forceinline__ void fold4(int* ix, float* wt) {
    if (ix[1] == ix[0]) { wt[0] += wt[1]; wt[1] = 0.0f; }
    if (ix[2] == ix[0]) { wt[0] += wt[2]; wt[2] = 0.0f; }
    else if (ix[2] == ix[1]) { wt[1] += wt[2]; wt[2] = 0.0f; }
    if (ix[3] == ix[0]) { wt[0] += wt[3]; wt[3] = 0.0f; }
    else if (ix[3] == ix[1]) { wt[1] += wt[3]; wt[3] = 0.0f; }
    else if (ix[3] == ix[2]) { wt[2] += wt[3]; wt[3] = 0.0f; }
}

// ---------- kernel 1: (B,C,THW) f32 -> (B,THW,C) bf16, tile 128ch x 32pos ----
__global__ __launch_bounds__(256) void transpose_kernel(
    const float* __restrict__ F, ushort* __restrict__ G)
{
    __shared__ float tile[128 * 33];
    int bid = blockIdx.x;
    int b = bid / (THW / 32);                 // THW/32 = 1568
    int pos0 = (bid - b * (THW / 32)) * 32;
    int t = threadIdx.x;

    const float* Fb = F + (size_t)b * C_ * THW + pos0;
    int cb = t >> 3, chunk = t & 7;
#pragma unroll
    for (int it = 0; it < 4; ++it) {
        int c = cb + it * 32;
        float4 v = *(const float4*)(Fb + (size_t)c * THW + chunk * 4);
        int a = (c >> 5) & 3;
        int base = c * 33 + ((chunk ^ a) << 2);
        tile[base + 0] = v.x; tile[base + 1] = v.y;
        tile[base + 2] = v.z; tile[base + 3] = v.w;
    }
    __syncthreads();

    int i = t & 15;
    ushort* Gp = G + ((size_t)b * THW + pos0) * C_ + (i << 3);
#pragma unroll
    for (int it = 0; it < 2; ++it) {
        int pos = (t >> 4) + it * 16;
        float f[8];
#pragma unroll
        for (int j = 0; j < 8; ++j) {
            int c = i * 8 + j;
            int a = (c >> 5) & 3;
            f[j] = tile[c * 33 + (pos ^ (a << 2))];
        }
        uint4 o;
        o.x = pk2(f[0], f[1]); o.y = pk2(f[2], f[3]);
        o.z = pk2(f[4], f[5]); o.w = pk2(f[6], f[7]);
        *(uint4*)(Gp + (size_t)pos * C_) = o;
    }
}

// ---------- kernel 2: gather sampler with full corner dedup ----------
__device__ __forceinline__ void acc8(float* acc, uint4 v, float wgt) {
    acc[0] += wgt * bf16lo(v.x); acc[1] += wgt * bf16hi(v.x);
    acc[2] += wgt * bf16lo(v.y); acc[3] += wgt * bf16hi(v.y);
    acc[4] += wgt * bf16lo(v.z); acc[5] += wgt * bf16hi(v.z);
    acc[6] += wgt * bf16lo(v.w); acc[7] += wgt * bf16hi(v.w);
}

__global__ __launch_bounds__(256, 8) void sample_kernel(
    const ushort* __restrict__ G,
    const float* __restrict__ rois,
    float* __restrict__ out)
{
    __shared__ float lds[16 * 132];
    int bid0 = blockIdx.x;
    int bid = (bid0 & 7) * 256 + (bid0 >> 3);   // bijective XCD swizzle (2048 % 8 == 0)
    int r = bid >> 4, sub = bid & 15;
    int ot = sub >> 2, ph = sub & 3;
    int t = threadIdx.x;
    int pp = t >> 4, i = t & 15;
    int pidx = ph * 16 + pp;
    int oh = pidx >> 3, ow = pidx & 7;          // oh wave-uniform, ow per 16-lane group

    const float* roi = rois + r * 7;
    int   b  = (int)roi[0];
    float ts = roi[1] * 0.25f,   te = roi[4] * 0.25f;
    float xs = roi[2] * 0.0625f, xe = roi[5] * 0.0625f;
    float ys = roi[3] * 0.0625f, ye = roi[6] * 0.0625f;
    float bin_t = fmaxf(te - ts, 1.0f) * 0.25f;
    float bin_y = fmaxf(ye - ys, 1.0f) * 0.125f;
    float bin_x = fmaxf(xe - xs, 1.0f) * 0.125f;

    int tl[2], th[2]; float wtl[2], wth[2]; bool vt[2];
    int yl[2], yh[2]; float wyl[2], wyh[2]; bool vy[2];
    int xl[2], xh[2]; float wxl[2], wxh[2]; bool vx[2];
#pragma unroll
    for (int s = 0; s < 2; ++s) {
        float sb = ((float)s + 0.5f) * 0.5f;
        axis_interp(ts + ((float)ot + sb) * bin_t, T_, tl[s], th[s], wtl[s], wth[s], vt[s]);
        axis_interp(ys + ((float)oh + sb) * bin_y, H_, yl[s], yh[s], wyl[s], wyh[s], vy[s]);
        axis_interp(xs + ((float)ow + sb) * bin_x, W_, xl[s], xh[s], wxl[s], wxh[s], vx[s]);
    }

    // ---- fold validity into weights; dedupe all axes into 4 static slots ----
    int   tix[4] = { tl[0], th[0], tl[1], th[1] };
    float twt[4] = { vt[0] ? wtl[0] : 0.0f, vt[0] ? wth[0] : 0.0f,
                     vt[1] ? wtl[1] : 0.0f, vt[1] ? wth[1] : 0.0f };
    fold4(tix, twt);

    int   yix[4] = { yl[0], yh[0], yl[1], yh[1] };
    float ywt[4] = { vy[0] ? wyl[0] : 0.0f, vy[0] ? wyh[0] : 0.0f,
                     vy[1] ? wyl[1] : 0.0f, vy[1] ? wyh[1] : 0.0f };
    fold4(yix, ywt);

    int   xof[4] = { xl[0] << 7, xh[0] << 7, xl[1] << 7, xh[1] << 7 };  // *C_
    float xwt[4] = { vx[0] ? wxl[0] : 0.0f, vx[0] ? wxh[0] : 0.0f,
                     vx[1] ? wxl[1] : 0.0f, vx[1] ? wxh[1] : 0.0f };
    fold4(xof, xwt);
    bool xnz[4] = { xwt[0] != 0.0f, xwt[1] != 0.0f, xwt[2] != 0.0f, xwt[3] != 0.0f };

    const ushort* Gb = G + (size_t)b * THW * C_ + (i << 3);
    float acc[8];
#pragma unroll
    for (int j = 0; j < 8; ++j) acc[j] = 0.0f;

#pragma unroll
    for (int ti = 0; ti < 4; ++ti) {
        float tw = twt[ti];
        if (tw == 0.0f) continue;               // block-uniform skip
        int tof = tix[ti] * HW;
#pragma unroll
        for (int yi = 0; yi < 4; ++yi) {
            float w = tw * ywt[yi];
            if (ywt[yi] == 0.0f) continue;      // wave-uniform skip
            const ushort* row = Gb + ((size_t)(tof + yix[yi] * W_) << 7);
            // predicated loads, hoisted before FMAs (zero-init avoids 0*NaN)
            uint4 a0 = make_uint4(0, 0, 0, 0), a1 = a0, a2 = a0, a3 = a0;
            if (xnz[0]) a0 = *(const uint4*)(row + xof[0]);
            if (xnz[1]) a1 = *(const uint4*)(row + xof[1]);
            if (xnz[2]) a2 = *(const uint4*)(row + xof[2]);
            if (xnz[3]) a3 = *(const uint4*)(row + xof[3]);
            acc8(acc, a0, w * xwt[0]);
            acc8(acc, a1, w * xwt[1]);
            acc8(acc, a2, w * xwt[2]);
            acc8(acc, a3, w * xwt[3]);
        }
    }

    float* lrow = lds + pp * 132 + (i << 3);
    *(float4*)lrow       = make_float4(acc[0] * 0.125f, acc[1] * 0.125f,
                                       acc[2] * 0.125f, acc[3] * 0.125f);
    *(float4*)(lrow + 4) = make_float4(acc[4] * 0.125f, acc[5] * 0.125f,
                                       acc[6] * 0.125f, acc[7] * 0.125f);
    __syncthreads();

    // coalesced store: per c, 16 consecutive positions (64B rows)
    float* outp = out + (size_t)r * C_ * 256 + ot * 64 + ph * 16;
#pragma unroll
    for (int it = 0; it < 2; ++it) {
        int c = (t >> 2) + it * 64;
        int p4 = (t & 3) * 4;
        float4 o = make_float4(lds[(p4 + 0) * 132 + c], lds[(p4 + 1) * 132 + c],
                               lds[(p4 + 2) * 132 + c], lds[(p4 + 3) * 132 + c]);
        *(float4*)(outp + (size_t)c * 256 + p4) = o;
    }
}

// ---------- fallback: direct gather (if ws too small) ----------
__global__ __launch_bounds__(256) void roialign3d_fallback(
    const float* __restrict__ features,
    const float* __restrict__ rois,
    float* __restrict__ out)
{
    int gid = blockIdx.x * 256 + threadIdx.x;
    int ow = gid & 7, oh = (gid >> 3) & 7, ot = (gid >> 6) & 3;
    int c = (gid >> 8) & 127, r = gid >> 15;
    const float* roi = rois + r * 7;
    int   b  = (int)roi[0];
    float ts = roi[1] * 0.25f,   te = roi[4] * 0.25f;
    float xs = roi[2] * 0.0625f, xe = roi[5] * 0.0625f;
    float ys = roi[3] * 0.0625f, ye = roi[6] * 0.0625f;
    float bin_t = fmaxf(te - ts, 1.0f) * 0.25f;
    float bin_y = fmaxf(ye - ys, 1.0f) * 0.125f;
    float bin_x = fmaxf(xe - xs, 1.0f) * 0.125f;
    int tl[2], th[2]; float wtl[2], wth[2]; bool vt[2];
    int yl[2], yh[2]; float wyl[2], wyh[2]; bool vy[2];
    int xl[2], xh[2]; float wxl[2], wxh[2]; bool vx[2];
#pragma unroll
    for (int s = 0; s < 2; ++s) {
        float sb = ((float)s + 0.5f) * 0.5f;
        axis_interp(ts + ((float)ot + sb) * bin_t, T_, tl[s], th[s], wtl[s], wth[s], vt[s]);
        axis_interp(ys + ((float)oh + sb) * bin_y, H_, yl[s], yh[s], wyl[s], wyh[s], vy[s]);
        axis_interp(xs + ((float)ow + sb) * bin_x, W_, xl[s], xh[s], wxl[s], wxh[s], vx[s]);
    }
    const float* f = features + (size_t)(b * C_ + c) * THW;
    float acc = 0.0f;
#pragma unroll
    for (int st = 0; st < 2; ++st)
#pragma unroll
        for (int sy = 0; sy < 2; ++sy)
#pragma unroll
            for (int sx = 0; sx < 2; ++sx)
                if (vt[st] && vy[sy] && vx[sx]) {
                    int o00 = tl[st] * HW + yl[sy] * W_;
                    int o01 = tl[st] * HW + yh[sy] * W_;
                    int o10 = th[st] * HW + yl[sy] * W_;
                    int o11 = th[st] * HW + yh[sy] * W_;
                    float v0 = wyl[sy] * (wxl[sx] * f[o00 + xl[sx]] + wxh[sx] * f[o00 + xh[sx]])
                             + wyh[sy] * (wxl[sx] * f[o01 + xl[sx]] + wxh[sx] * f[o01 + xh[sx]]);
                    float v1 = wyl[sy] * (wxl[sx] * f[o10 + xl[sx]] + wxh[sx] * f[o10 + xh[sx]])
                             + wyh[sy] * (wxl[sx] * f[o11 + xl[sx]] + wxh[sx] * f[o11 + xh[sx]]);
                    acc += wtl[st] * v0 + wth[st] * v1;
                }
    out[gid] = acc * 0.125f;
}

extern "C" void kernel_launch(void* const* d_in, const int* in_sizes, int n_in,
                              void* d_out, int out_size, void* d_ws, size_t ws_size,
                              hipStream_t stream) {
    const float* features = (const float*)d_in[0];
    const float* rois     = (const float*)d_in[1];
    float* out            = (float*)d_out;

    if (ws_size >= G_BYTES) {
        ushort* G = (ushort*)d_ws;
        transpose_kernel<<<B_ * (THW / 32), 256, 0, stream>>>(features, G);
        sample_kernel<<<R_ * OT * 4, 256, 0, stream>>>(G, rois, out);
    } else {
        int total = R_ * C_ * OT * OH * OW;
        roialign3d_fallback<<<total / 256, 256, 0, stream>>>(features, rois, out);
    }
}

// Round 7
// 47.361 us; speedup vs baseline: 1.3281x; 1.3281x over previous
//
#include <hip/hip_runtime.h>
#include <hip/hip_bf16.h>

// RoIAlign3D: features (B=4,C=128,T=16,H=56,W=56) f32, rois (R=128,7) f32
// out (R,C,4,8,8) f32. S=2 sub-samples per axis, mean-pooled.
//
// Pass 1: transpose features -> channel-last bf16 G[b][t][h][w][c] in d_ws.
// Pass 2: gather, t/y corner dedup via weight-folding (uniform skips only),
//         2 output positions per thread (same oh) -> 8 independent loads in
//         flight per row iteration (2x MLP vs r4). No forced occupancy cap.

constexpr int B_ = 4, C_ = 128, T_ = 16, H_ = 56, W_ = 56, R_ = 128;
constexpr int OT = 4, OH = 8, OW = 8;
constexpr int HW = H_ * W_;       // 3136
constexpr int THW = T_ * HW;      // 50176
constexpr size_t G_BYTES = (size_t)B_ * THW * C_ * 2;   // 51,380,224

__device__ __forceinline__ float bf16lo(unsigned u) { return __uint_as_float(u << 16); }
__device__ __forceinline__ float bf16hi(unsigned u) { return __uint_as_float(u & 0xffff0000u); }

__device__ __forceinline__ unsigned pk2(float lo, float hi) {
    unsigned a = (unsigned)__bfloat16_as_ushort(__float2bfloat16(lo));
    unsigned b = (unsigned)__bfloat16_as_ushort(__float2bfloat16(hi));
    return a | (b << 16);
}

__device__ __forceinline__ void axis_interp(float coord, int size,
                                            int& lo, int& hi,
                                            float& wl, float& wh, bool& valid) {
    valid = (coord >= -1.0f) && (coord <= (float)size);
    float c = fminf(fmaxf(coord, 0.0f), (float)(size - 1));
    lo = (int)floorf(c);
    if (lo > size - 1) lo = size - 1;
    hi = min(lo + 1, size - 1);
    float fr = c - (float)lo;
    wl = 1.0f - fr;
    wh = fr;
}

// fold 4 (index,weight) slots: merge duplicate indices into first occurrence
__device__ __forceinline__ void fold4(int* ix, float* wt) {
    if (ix[1] == ix[0]) { wt[0] += wt[1]; wt[1] = 0.0f; }
    if (ix[2] == ix[0]) { wt[0] += wt[2]; wt[2] = 0.0f; }
    else if (ix[2] == ix[1]) { wt[1] += wt[2]; wt[2] = 0.0f; }
    if (ix[3] == ix[0]) { wt[0] += wt[3]; wt[3] = 0.0f; }
    else if (ix[3] == ix[1]) { wt[1] += wt[3]; wt[3] = 0.0f; }
    else if (ix[3] == ix[2]) { wt[2] += wt[3]; wt[3] = 0.0f; }
}

// ---------- kernel 1: (B,C,THW) f32 -> (B,THW,C) bf16, tile 128ch x 32pos ----
__global__ __launch_bounds__(256) void transpose_kernel(
    const float* __restrict__ F, ushort* __restrict__ G)
{
    __shared__ float tile[128 * 33];
    int bid = blockIdx.x;
    int b = bid / (THW / 32);                 // THW/32 = 1568
    int pos0 = (bid - b * (THW / 32)) * 32;
    int t = threadIdx.x;

    const float* Fb = F + (size_t)b * C_ * THW + pos0;
    int cb = t >> 3, chunk = t & 7;
#pragma unroll
    for (int it = 0; it < 4; ++it) {
        int c = cb + it * 32;
        float4 v = *(const float4*)(Fb + (size_t)c * THW + chunk * 4);
        int a = (c >> 5) & 3;
        int base = c * 33 + ((chunk ^ a) << 2);
        tile[base + 0] = v.x; tile[base + 1] = v.y;
        tile[base + 2] = v.z; tile[base + 3] = v.w;
    }
    __syncthreads();

    int i = t & 15;
    ushort* Gp = G + ((size_t)b * THW + pos0) * C_ + (i << 3);
#pragma unroll
    for (int it = 0; it < 2; ++it) {
        int pos = (t >> 4) + it * 16;
        float f[8];
#pragma unroll
        for (int j = 0; j < 8; ++j) {
            int c = i * 8 + j;
            int a = (c >> 5) & 3;
            f[j] = tile[c * 33 + (pos ^ (a << 2))];
        }
        uint4 o;
        o.x = pk2(f[0], f[1]); o.y = pk2(f[2], f[3]);
        o.z = pk2(f[4], f[5]); o.w = pk2(f[6], f[7]);
        *(uint4*)(Gp + (size_t)pos * C_) = o;
    }
}

// ---------- kernel 2: gather sampler, 2 positions/thread ----------
__device__ __forceinline__ void acc8(float* acc, uint4 v, float wgt) {
    acc[0] += wgt * bf16lo(v.x); acc[1] += wgt * bf16hi(v.x);
    acc[2] += wgt * bf16lo(v.y); acc[3] += wgt * bf16hi(v.y);
    acc[4] += wgt * bf16lo(v.z); acc[5] += wgt * bf16hi(v.z);
    acc[6] += wgt * bf16lo(v.w); acc[7] += wgt * bf16hi(v.w);
}

__global__ __launch_bounds__(256, 4) void sample_kernel(
    const ushort* __restrict__ G,
    const float* __restrict__ rois,
    float* __restrict__ out)
{
    __shared__ float lds[32 * 132];
    int bid0 = blockIdx.x;
    int bid = (bid0 & 7) * 128 + (bid0 >> 3);   // bijective XCD swizzle (1024 % 8 == 0)
    int r = bid >> 3, sub = bid & 7;
    int ot = sub >> 1, half = sub & 1;
    int t = threadIdx.x;
    int pp = t >> 4, i = t & 15;                // pp: 16 position-pairs, i: ch-slice
    int oh_l = pp >> 2;                         // 0..3 (wave-uniform: wave covers one oh_l... pp 0..3 per wave)
    int oh = half * 4 + oh_l;
    int owA = pp & 3, owB = owA + 4;

    const float* roi = rois + r * 7;
    int   b  = (int)roi[0];
    float ts = roi[1] * 0.25f,   te = roi[4] * 0.25f;
    float xs = roi[2] * 0.0625f, xe = roi[5] * 0.0625f;
    float ys = roi[3] * 0.0625f, ye = roi[6] * 0.0625f;
    float bin_t = fmaxf(te - ts, 1.0f) * 0.25f;
    float bin_y = fmaxf(ye - ys, 1.0f) * 0.125f;
    float bin_x = fmaxf(xe - xs, 1.0f) * 0.125f;

    int tl[2], th[2]; float wtl[2], wth[2]; bool vt[2];
    int yl[2], yh[2]; float wyl[2], wyh[2]; bool vy[2];
    int xlA[2], xhA[2]; float wxlA[2], wxhA[2]; bool vxA[2];
    int xlB[2], xhB[2]; float wxlB[2], wxhB[2]; bool vxB[2];
#pragma unroll
    for (int s = 0; s < 2; ++s) {
        float sb = ((float)s + 0.5f) * 0.5f;
        axis_interp(ts + ((float)ot + sb) * bin_t, T_, tl[s], th[s], wtl[s], wth[s], vt[s]);
        axis_interp(ys + ((float)oh + sb) * bin_y, H_, yl[s], yh[s], wyl[s], wyh[s], vy[s]);
        axis_interp(xs + ((float)owA + sb) * bin_x, W_, xlA[s], xhA[s], wxlA[s], wxhA[s], vxA[s]);
        axis_interp(xs + ((float)owB + sb) * bin_x, W_, xlB[s], xhB[s], wxlB[s], wxhB[s], vxB[s]);
    }

    // ---- fold validity into weights; dedupe t and y into 4 static slots ----
    int   tix[4] = { tl[0], th[0], tl[1], th[1] };
    float twt[4] = { vt[0] ? wtl[0] : 0.0f, vt[0] ? wth[0] : 0.0f,
                     vt[1] ? wtl[1] : 0.0f, vt[1] ? wth[1] : 0.0f };
    fold4(tix, twt);

    int   yix[4] = { yl[0], yh[0], yl[1], yh[1] };
    float ywt[4] = { vy[0] ? wyl[0] : 0.0f, vy[0] ? wyh[0] : 0.0f,
                     vy[1] ? wyl[1] : 0.0f, vy[1] ? wyh[1] : 0.0f };
    fold4(yix, ywt);

    int   xofA[4] = { xlA[0] << 7, xhA[0] << 7, xlA[1] << 7, xhA[1] << 7 };
    float xwtA[4] = { vxA[0] ? wxlA[0] : 0.0f, vxA[0] ? wxhA[0] : 0.0f,
                      vxA[1] ? wxlA[1] : 0.0f, vxA[1] ? wxhA[1] : 0.0f };
    int   xofB[4] = { xlB[0] << 7, xhB[0] << 7, xlB[1] << 7, xhB[1] << 7 };
    float xwtB[4] = { vxB[0] ? wxlB[0] : 0.0f, vxB[0] ? wxhB[0] : 0.0f,
                      vxB[1] ? wxlB[1] : 0.0f, vxB[1] ? wxhB[1] : 0.0f };

    const ushort* Gb = G + (size_t)b * THW * C_ + (i << 3);
    float accA[8], accB[8];
#pragma unroll
    for (int j = 0; j < 8; ++j) { accA[j] = 0.0f; accB[j] = 0.0f; }

#pragma unroll
    for (int ti = 0; ti < 4; ++ti) {
        float tw = twt[ti];
        if (tw == 0.0f) continue;               // block-uniform skip
        int tof = tix[ti] * HW;
#pragma unroll
        for (int yi = 0; yi < 4; ++yi) {
            float w = tw * ywt[yi];
            if (ywt[yi] == 0.0f) continue;      // wave-uniform skip
            const ushort* row = Gb + ((size_t)(tof + yix[yi] * W_) << 7);
            uint4 a0 = *(const uint4*)(row + xofA[0]);
            uint4 a1 = *(const uint4*)(row + xofA[1]);
            uint4 a2 = *(const uint4*)(row + xofA[2]);
            uint4 a3 = *(const uint4*)(row + xofA[3]);
            uint4 b0 = *(const uint4*)(row + xofB[0]);
            uint4 b1 = *(const uint4*)(row + xofB[1]);
            uint4 b2 = *(const uint4*)(row + xofB[2]);
            uint4 b3 = *(const uint4*)(row + xofB[3]);
            acc8(accA, a0, w * xwtA[0]);
            acc8(accA, a1, w * xwtA[1]);
            acc8(accA, a2, w * xwtA[2]);
            acc8(accA, a3, w * xwtA[3]);
            acc8(accB, b0, w * xwtB[0]);
            acc8(accB, b1, w * xwtB[1]);
            acc8(accB, b2, w * xwtB[2]);
            acc8(accB, b3, w * xwtB[3]);
        }
    }

    int lpA = oh_l * 8 + owA, lpB = oh_l * 8 + owB;
    float* lrowA = lds + lpA * 132 + (i << 3);
    float* lrowB = lds + lpB * 132 + (i << 3);
    *(float4*)lrowA       = make_float4(accA[0] * 0.125f, accA[1] * 0.125f,
                                        accA[2] * 0.125f, accA[3] * 0.125f);
    *(float4*)(lrowA + 4) = make_float4(accA[4] * 0.125f, accA[5] * 0.125f,
                                        accA[6] * 0.125f, accA[7] * 0.125f);
    *(float4*)lrowB       = make_float4(accB[0] * 0.125f, accB[1] * 0.125f,
                                        accB[2] * 0.125f, accB[3] * 0.125f);
    *(float4*)(lrowB + 4) = make_float4(accB[4] * 0.125f, accB[5] * 0.125f,
                                        accB[6] * 0.125f, accB[7] * 0.125f);
    __syncthreads();

    // coalesced store: per c, 32 consecutive positions (128B rows)
    float* outp = out + (size_t)r * C_ * 256 + ot * 64 + half * 32;
    int c0 = t >> 3, p4 = (t & 7) * 4;
#pragma unroll
    for (int j = 0; j < 4; ++j) {
        int c = c0 + j * 32;
        float4 o = make_float4(lds[(p4 + 0) * 132 + c], lds[(p4 + 1) * 132 + c],
                               lds[(p4 + 2) * 132 + c], lds[(p4 + 3) * 132 + c]);
        *(float4*)(outp + (size_t)c * 256 + p4) = o;
    }
}

// ---------- fallback: direct gather (if ws too small) ----------
__global__ __launch_bounds__(256) void roialign3d_fallback(
    const float* __restrict__ features,
    const float* __restrict__ rois,
    float* __restrict__ out)
{
    int gid = blockIdx.x * 256 + threadIdx.x;
    int ow = gid & 7, oh = (gid >> 3) & 7, ot = (gid >> 6) & 3;
    int c = (gid >> 8) & 127, r = gid >> 15;
    const float* roi = rois + r * 7;
    int   b  = (int)roi[0];
    float ts = roi[1] * 0.25f,   te = roi[4] * 0.25f;
    float xs = roi[2] * 0.0625f, xe = roi[5] * 0.0625f;
    float ys = roi[3] * 0.0625f, ye = roi[6] * 0.0625f;
    float bin_t = fmaxf(te - ts, 1.0f) * 0.25f;
    float bin_y = fmaxf(ye - ys, 1.0f) * 0.125f;
    float bin_x = fmaxf(xe - xs, 1.0f) * 0.125f;
    int tl[2], th[2]; float wtl[2], wth[2]; bool vt[2];
    int yl[2], yh[2]; float wyl[2], wyh[2]; bool vy[2];
    int xl[2], xh[2]; float wxl[2], wxh[2]; bool vx[2];
#pragma unroll
    for (int s = 0; s < 2; ++s) {
        float sb = ((float)s + 0.5f) * 0.5f;
        axis_interp(ts + ((float)ot + sb) * bin_t, T_, tl[s], th[s], wtl[s], wth[s], vt[s]);
        axis_interp(ys + ((float)oh + sb) * bin_y, H_, yl[s], yh[s], wyl[s], wyh[s], vy[s]);
        axis_interp(xs + ((float)ow + sb) * bin_x, W_, xl[s], xh[s], wxl[s], wxh[s], vx[s]);
    }
    const float* f = features + (size_t)(b * C_ + c) * THW;
    float acc = 0.0f;
#pragma unroll
    for (int st = 0; st < 2; ++st)
#pragma unroll
        for (int sy = 0; sy < 2; ++sy)
#pragma unroll
            for (int sx = 0; sx < 2; ++sx)
                if (vt[st] && vy[sy] && vx[sx]) {
                    int o00 = tl[st] * HW + yl[sy] * W_;
                    int o01 = tl[st] * HW + yh[sy] * W_;
                    int o10 = th[st] * HW + yl[sy] * W_;
                    int o11 = th[st] * HW + yh[sy] * W_;
                    float v0 = wyl[sy] * (wxl[sx] * f[o00 + xl[sx]] + wxh[sx] * f[o00 + xh[sx]])
                             + wyh[sy] * (wxl[sx] * f[o01 + xl[sx]] + wxh[sx] * f[o01 + xh[sx]]);
                    float v1 = wyl[sy] * (wxl[sx] * f[o10 + xl[sx]] + wxh[sx] * f[o10 + xh[sx]])
                             + wyh[sy] * (wxl[sx] * f[o11 + xl[sx]] + wxh[sx] * f[o11 + xh[sx]]);
                    acc += wtl[st] * v0 + wth[st] * v1;
                }
    out[gid] = acc * 0.125f;
}

extern "C" void kernel_launch(void* const* d_in, const int* in_sizes, int n_in,
                              void* d_out, int out_size, void* d_ws, size_t ws_size,
                              hipStream_t stream) {
    const float* features = (const float*)d_in[0];
    const float* rois     = (const float*)d_in[1];
    float* out            = (float*)d_out;

    if (ws_size >= G_BYTES) {
        ushort* G = (ushort*)d_ws;
        transpose_kernel<<<B_ * (THW / 32), 256, 0, stream>>>(features, G);
        sample_kernel<<<R_ * OT * 2, 256, 0, stream>>>(G, rois, out);
    } else {
        int total = R_ * C_ * OT * OH * OW;
        roialign3d_fallback<<<total / 256, 256, 0, stream>>>(features, rois, out);
    }
}

// Round 8
// 46.257 us; speedup vs baseline: 1.3598x; 1.0239x over previous
//
#include <hip/hip_runtime.h>
#include <hip/hip_bf16.h>

// RoIAlign3D: features (B=4,C=128,T=16,H=56,W=56) f32, rois (R=128,7) f32
// out (R,C,4,8,8) f32. S=2 sub-samples per axis, mean-pooled.
//
// Pass 1: transpose features -> channel-last bf16 G[b][t][h][w][c] in d_ws.
// Pass 2: gather, t/y corner dedup via weight-folding (uniform skips only),
//         1 output position per thread (lean VGPR), 6 blocks/CU (24 waves/CU).

constexpr int B_ = 4, C_ = 128, T_ = 16, H_ = 56, W_ = 56, R_ = 128;
constexpr int OT = 4, OH = 8, OW = 8;
constexpr int HW = H_ * W_;       // 3136
constexpr int THW = T_ * HW;      // 50176
constexpr size_t G_BYTES = (size_t)B_ * THW * C_ * 2;   // 51,380,224

__device__ __forceinline__ float bf16lo(unsigned u) { return __uint_as_float(u << 16); }
__device__ __forceinline__ float bf16hi(unsigned u) { return __uint_as_float(u & 0xffff0000u); }

__device__ __forceinline__ unsigned pk2(float lo, float hi) {
    unsigned a = (unsigned)__bfloat16_as_ushort(__float2bfloat16(lo));
    unsigned b = (unsigned)__bfloat16_as_ushort(__float2bfloat16(hi));
    return a | (b << 16);
}

__device__ __forceinline__ void axis_interp(float coord, int size,
                                            int& lo, int& hi,
                                            float& wl, float& wh, bool& valid) {
    valid = (coord >= -1.0f) && (coord <= (float)size);
    float c = fminf(fmaxf(coord, 0.0f), (float)(size - 1));
    lo = (int)floorf(c);
    if (lo > size - 1) lo = size - 1;
    hi = min(lo + 1, size - 1);
    float fr = c - (float)lo;
    wl = 1.0f - fr;
    wh = fr;
}

// fold 4 (index,weight) slots: merge duplicate indices into first occurrence
__device__ __forceinline__ void fold4(int* ix, float* wt) {
    if (ix[1] == ix[0]) { wt[0] += wt[1]; wt[1] = 0.0f; }
    if (ix[2] == ix[0]) { wt[0] += wt[2]; wt[2] = 0.0f; }
    else if (ix[2] == ix[1]) { wt[1] += wt[2]; wt[2] = 0.0f; }
    if (ix[3] == ix[0]) { wt[0] += wt[3]; wt[3] = 0.0f; }
    else if (ix[3] == ix[1]) { wt[1] += wt[3]; wt[3] = 0.0f; }
    else if (ix[3] == ix[2]) { wt[2] += wt[3]; wt[3] = 0.0f; }
}

// ---------- kernel 1: (B,C,THW) f32 -> (B,THW,C) bf16, tile 128ch x 32pos ----
__global__ __launch_bounds__(256) void transpose_kernel(
    const float* __restrict__ F, ushort* __restrict__ G)
{
    __shared__ float tile[128 * 33];
    int bid = blockIdx.x;
    int b = bid / (THW / 32);                 // THW/32 = 1568
    int pos0 = (bid - b * (THW / 32)) * 32;
    int t = threadIdx.x;

    const float* Fb = F + (size_t)b * C_ * THW + pos0;
    int cb = t >> 3, chunk = t & 7;
#pragma unroll
    for (int it = 0; it < 4; ++it) {
        int c = cb + it * 32;
        float4 v = *(const float4*)(Fb + (size_t)c * THW + chunk * 4);
        int a = (c >> 5) & 3;
        int base = c * 33 + ((chunk ^ a) << 2);
        tile[base + 0] = v.x; tile[base + 1] = v.y;
        tile[base + 2] = v.z; tile[base + 3] = v.w;
    }
    __syncthreads();

    int i = t & 15;
    ushort* Gp = G + ((size_t)b * THW + pos0) * C_ + (i << 3);
#pragma unroll
    for (int it = 0; it < 2; ++it) {
        int pos = (t >> 4) + it * 16;
        float f[8];
#pragma unroll
        for (int j = 0; j < 8; ++j) {
            int c = i * 8 + j;
            int a = (c >> 5) & 3;
            f[j] = tile[c * 33 + (pos ^ (a << 2))];
        }
        uint4 o;
        o.x = pk2(f[0], f[1]); o.y = pk2(f[2], f[3]);
        o.z = pk2(f[4], f[5]); o.w = pk2(f[6], f[7]);
        *(uint4*)(Gp + (size_t)pos * C_) = o;
    }
}

// ---------- kernel 2: gather sampler, 1 position/thread, 24 waves/CU ----------
__device__ __forceinline__ void acc8(float* acc, uint4 v, float wgt) {
    acc[0] += wgt * bf16lo(v.x); acc[1] += wgt * bf16hi(v.x);
    acc[2] += wgt * bf16lo(v.y); acc[3] += wgt * bf16hi(v.y);
    acc[4] += wgt * bf16lo(v.z); acc[5] += wgt * bf16hi(v.z);
    acc[6] += wgt * bf16lo(v.w); acc[7] += wgt * bf16hi(v.w);
}

__global__ __launch_bounds__(256, 6) void sample_kernel(
    const ushort* __restrict__ G,
    const float* __restrict__ rois,
    float* __restrict__ out)
{
    __shared__ float lds[16 * 132];
    int bid0 = blockIdx.x;
    int bid = (bid0 & 7) * 256 + (bid0 >> 3);   // bijective XCD swizzle (2048 % 8 == 0)
    int r = bid >> 4, sub = bid & 15;
    int ot = sub >> 2, ph = sub & 3;
    int t = threadIdx.x;
    int pp = t >> 4, i = t & 15;
    int pidx = ph * 16 + pp;
    int oh = pidx >> 3, ow = pidx & 7;          // oh wave-uniform, ow per 16-lane group

    const float* roi = rois + r * 7;
    int   b  = (int)roi[0];
    float ts = roi[1] * 0.25f,   te = roi[4] * 0.25f;
    float xs = roi[2] * 0.0625f, xe = roi[5] * 0.0625f;
    float ys = roi[3] * 0.0625f, ye = roi[6] * 0.0625f;
    float bin_t = fmaxf(te - ts, 1.0f) * 0.25f;
    float bin_y = fmaxf(ye - ys, 1.0f) * 0.125f;
    float bin_x = fmaxf(xe - xs, 1.0f) * 0.125f;

    int tl[2], th[2]; float wtl[2], wth[2]; bool vt[2];
    int yl[2], yh[2]; float wyl[2], wyh[2]; bool vy[2];
    int xl[2], xh[2]; float wxl[2], wxh[2]; bool vx[2];
#pragma unroll
    for (int s = 0; s < 2; ++s) {
        float sb = ((float)s + 0.5f) * 0.5f;
        axis_interp(ts + ((float)ot + sb) * bin_t, T_, tl[s], th[s], wtl[s], wth[s], vt[s]);
        axis_interp(ys + ((float)oh + sb) * bin_y, H_, yl[s], yh[s], wyl[s], wyh[s], vy[s]);
        axis_interp(xs + ((float)ow + sb) * bin_x, W_, xl[s], xh[s], wxl[s], wxh[s], vx[s]);
    }

    // ---- fold validity into weights; dedupe t and y into 4 static slots ----
    int   tix[4] = { tl[0], th[0], tl[1], th[1] };
    float twt[4] = { vt[0] ? wtl[0] : 0.0f, vt[0] ? wth[0] : 0.0f,
                     vt[1] ? wtl[1] : 0.0f, vt[1] ? wth[1] : 0.0f };
    fold4(tix, twt);
    // fold the 1/8 sub-sample mean into the t-weights (saves epilogue mults)
    twt[0] *= 0.125f; twt[1] *= 0.125f; twt[2] *= 0.125f; twt[3] *= 0.125f;

    int   yix[4] = { yl[0], yh[0], yl[1], yh[1] };
    float ywt[4] = { vy[0] ? wyl[0] : 0.0f, vy[0] ? wyh[0] : 0.0f,
                     vy[1] ? wyl[1] : 0.0f, vy[1] ? wyh[1] : 0.0f };
    fold4(yix, ywt);

    int   xof[4] = { xl[0] << 7, xh[0] << 7, xl[1] << 7, xh[1] << 7 };  // *C_
    float xwt[4] = { vx[0] ? wxl[0] : 0.0f, vx[0] ? wxh[0] : 0.0f,
                     vx[1] ? wxl[1] : 0.0f, vx[1] ? wxh[1] : 0.0f };

    const ushort* Gb = G + (size_t)b * THW * C_ + (i << 3);
    float acc[8];
#pragma unroll
    for (int j = 0; j < 8; ++j) acc[j] = 0.0f;

#pragma unroll
    for (int ti = 0; ti < 4; ++ti) {
        float tw = twt[ti];
        if (tw == 0.0f) continue;               // block-uniform skip
        int tof = tix[ti] * HW;
#pragma unroll
        for (int yi = 0; yi < 4; ++yi) {
            float w = tw * ywt[yi];
            if (ywt[yi] == 0.0f) continue;      // wave-uniform skip
            const ushort* row = Gb + ((size_t)(tof + yix[yi] * W_) << 7);
            uint4 a0 = *(const uint4*)(row + xof[0]);
            uint4 a1 = *(const uint4*)(row + xof[1]);
            uint4 a2 = *(const uint4*)(row + xof[2]);
            uint4 a3 = *(const uint4*)(row + xof[3]);
            acc8(acc, a0, w * xwt[0]);
            acc8(acc, a1, w * xwt[1]);
            acc8(acc, a2, w * xwt[2]);
            acc8(acc, a3, w * xwt[3]);
        }
    }

    float* lrow = lds + pp * 132 + (i << 3);
    *(float4*)lrow       = make_float4(acc[0], acc[1], acc[2], acc[3]);
    *(float4*)(lrow + 4) = make_float4(acc[4], acc[5], acc[6], acc[7]);
    __syncthreads();

    // coalesced store: per c, 16 consecutive positions (64B rows)
    float* outp = out + (size_t)r * C_ * 256 + ot * 64 + ph * 16;
#pragma unroll
    for (int it = 0; it < 2; ++it) {
        int c = (t >> 2) + it * 64;
        int p4 = (t & 3) * 4;
        float4 o = make_float4(lds[(p4 + 0) * 132 + c], lds[(p4 + 1) * 132 + c],
                               lds[(p4 + 2) * 132 + c], lds[(p4 + 3) * 132 + c]);
        *(float4*)(outp + (size_t)c * 256 + p4) = o;
    }
}

// ---------- fallback: direct gather (if ws too small) ----------
__global__ __launch_bounds__(256) void roialign3d_fallback(
    const float* __restrict__ features,
    const float* __restrict__ rois,
    float* __restrict__ out)
{
    int gid = blockIdx.x * 256 + threadIdx.x;
    int ow = gid & 7, oh = (gid >> 3) & 7, ot = (gid >> 6) & 3;
    int c = (gid >> 8) & 127, r = gid >> 15;
    const float* roi = rois + r * 7;
    int   b  = (int)roi[0];
    float ts = roi[1] * 0.25f,   te = roi[4] * 0.25f;
    float xs = roi[2] * 0.0625f, xe = roi[5] * 0.0625f;
    float ys = roi[3] * 0.0625f, ye = roi[6] * 0.0625f;
    float bin_t = fmaxf(te - ts, 1.0f) * 0.25f;
    float bin_y = fmaxf(ye - ys, 1.0f) * 0.125f;
    float bin_x = fmaxf(xe - xs, 1.0f) * 0.125f;
    int tl[2], th[2]; float wtl[2], wth[2]; bool vt[2];
    int yl[2], yh[2]; float wyl[2], wyh[2]; bool vy[2];
    int xl[2], xh[2]; float wxl[2], wxh[2]; bool vx[2];
#pragma unroll
    for (int s = 0; s < 2; ++s) {
        float sb = ((float)s + 0.5f) * 0.5f;
        axis_interp(ts + ((float)ot + sb) * bin_t, T_, tl[s], th[s], wtl[s], wth[s], vt[s]);
        axis_interp(ys + ((float)oh + sb) * bin_y, H_, yl[s], yh[s], wyl[s], wyh[s], vy[s]);
        axis_interp(xs + ((float)ow + sb) * bin_x, W_, xl[s], xh[s], wxl[s], wxh[s], vx[s]);
    }
    const float* f = features + (size_t)(b * C_ + c) * THW;
    float acc = 0.0f;
#pragma unroll
    for (int st = 0; st < 2; ++st)
#pragma unroll
        for (int sy = 0; sy < 2; ++sy)
#pragma unroll
            for (int sx = 0; sx < 2; ++sx)
                if (vt[st] && vy[sy] && vx[sx]) {
                    int o00 = tl[st] * HW + yl[sy] * W_;
                    int o01 = tl[st] * HW + yh[sy] * W_;
                    int o10 = th[st] * HW + yl[sy] * W_;
                    int o11 = th[st] * HW + yh[sy] * W_;
                    float v0 = wyl[sy] * (wxl[sx] * f[o00 + xl[sx]] + wxh[sx] * f[o00 + xh[sx]])
                             + wyh[sy] * (wxl[sx] * f[o01 + xl[sx]] + wxh[sx] * f[o01 + xh[sx]]);
                    float v1 = wyl[sy] * (wxl[sx] * f[o10 + xl[sx]] + wxh[sx] * f[o10 + xh[sx]])
                             + wyh[sy] * (wxl[sx] * f[o11 + xl[sx]] + wxh[sx] * f[o11 + xh[sx]]);
                    acc += wtl[st] * v0 + wth[st] * v1;
                }
    out[gid] = acc * 0.125f;
}

extern "C" void kernel_launch(void* const* d_in, const int* in_sizes, int n_in,
                              void* d_out, int out_size, void* d_ws, size_t ws_size,
                              hipStream_t stream) {
    const float* features = (const float*)d_in[0];
    const float* rois     = (const float*)d_in[1];
    float* out            = (float*)d_out;

    if (ws_size >= G_BYTES) {
        ushort* G = (ushort*)d_ws;
        transpose_kernel<<<B_ * (THW / 32), 256, 0, stream>>>(features, G);
        sample_kernel<<<R_ * OT * 4, 256, 0, stream>>>(G, rois, out);
    } else {
        int total = R_ * C_ * OT * OH * OW;
        roialign3d_fallback<<<total / 256, 256, 0, stream>>>(features, rois, out);
    }
}